// Round 6
// baseline (343.600 us; speedup 1.0000x reference)
//
#include <hip/hip_runtime.h>
#include <stdint.h>
#include <cmath>

typedef short short8 __attribute__((ext_vector_type(8)));
typedef float f32x4 __attribute__((ext_vector_type(4)));

struct ResArr { float r[16]; };
struct DOff { int off[5]; };

__device__ __forceinline__ uint16_t f2bf(float f) {
  uint32_t u;
  __builtin_memcpy(&u, &f, 4);
  uint32_t r = (u + 0x7FFFu + ((u >> 16) & 1u)) >> 16;  // RNE
  return (uint16_t)r;
}

__device__ __forceinline__ uint32_t enc8(float v) {
  int q = __float2int_rn(v * 2048.0f);
  q = max(-127, min(127, q));
  return (uint32_t)(q & 0xFF);
}

// ---------------- prep: f32 table -> int8 pairs (1 dword = 2 entries) ----
__global__ __launch_bounds__(256) void tbl_i8_kernel(
    const float4* __restrict__ t4, uint32_t* __restrict__ o, int n) {
  int i = blockIdx.x * 256 + threadIdx.x;
  int stride = gridDim.x * 256;
  for (; i < n; i += stride) {
    float4 v = t4[i];
    o[i] = enc8(v.x) | (enc8(v.y) << 8) | (enc8(v.z) << 16) | (enc8(v.w) << 24);
  }
}

// ---------------- prep: dense re-indexed tables for levels 0..4 ----------
__global__ __launch_bounds__(256) void dense_build_kernel(
    const float* __restrict__ tablef, uint32_t* __restrict__ dt,
    DOff doffs, ResArr ra, int T) {
  int lvl = blockIdx.y;  // 0..4
  int r = (int)ra.r[lvl];
  int rp = r + 1;
  int n = rp * rp * r;
  uint32_t mask = (uint32_t)(T - 1);
  const float* tb = tablef + (size_t)lvl * (size_t)T * 2;
  uint32_t* out = dt + doffs.off[lvl];
  for (int i = blockIdx.x * 256 + threadIdx.x; i < n; i += gridDim.x * 256) {
    int z = i % r;
    int t = i / r;
    int y = t % rp;
    int x = t / rp;
    uint32_t hy = (uint32_t)y * 2654435761u;
    uint32_t h0 = ((uint32_t)x ^ hy ^ (uint32_t)z * 805459861u) & mask;
    uint32_t h1 = ((uint32_t)x ^ hy ^ (uint32_t)(z + 1) * 805459861u) & mask;
    float a0 = tb[h0 * 2], a1 = tb[h0 * 2 + 1];
    float c0 = tb[h1 * 2], c1 = tb[h1 * 2 + 1];
    out[i] = enc8(a0) | (enc8(a1) << 8) | (enc8(c0) << 16) | (enc8(c1) << 24);
  }
}

// ---------------- prep: pack weights into MFMA B-fragment order (bf16) ----
__global__ __launch_bounds__(256) void prep_pack_kernel(
    const float* __restrict__ W1, const float* __restrict__ W2,
    const float* __restrict__ W3, uint16_t* __restrict__ pW1,
    uint16_t* __restrict__ pW2, uint16_t* __restrict__ pW3) {
  int i = blockIdx.x * 256 + threadIdx.x;
  if (i < 4096) {
    int j = i & 7, lane = (i >> 3) & 63, t = i >> 9;
    int k = (lane >> 4) * 8 + j, col = t * 16 + (lane & 15);
    pW1[i] = f2bf(W1[k * 128 + col]);
  } else if (i < 20480) {
    int q = i - 4096;
    int j = q & 7, lane = (q >> 3) & 63, st = q >> 9;
    int s = st & 3, t = st >> 2;
    int k = s * 32 + (lane >> 4) * 8 + j, col = t * 16 + (lane & 15);
    pW2[q] = f2bf(W2[k * 128 + col]);
  } else if (i < 26624) {
    int q = i - 20480;
    int j = q & 7, lane = (q >> 3) & 63, st = q >> 9;
    int s = st & 3, t = st >> 2;
    int k = s * 32 + (lane >> 4) * 8 + j, col = t * 16 + (lane & 15);
    pW3[q] = (col < 42) ? f2bf(W3[k * 42 + col]) : (uint16_t)0;
  }
}

// b1' = b1 + cond @ W1[32:160]
__global__ void prep_b1p_kernel(const float* __restrict__ b1,
                                const float* __restrict__ cond,
                                const float* __restrict__ W1,
                                float* __restrict__ b1p) {
  int j = threadIdx.x;  // 128 threads
  float acc = b1[j];
  for (int c = 0; c < 128; ++c) acc += cond[c] * W1[(32 + c) * 128 + j];
  b1p[j] = acc;
}

// ---------------- hash grid encode v6: ALL LEVELS FUSED, point-per-lane --
// One thread = one point, all 16 levels. ~100 independent gather loads per
// thread = deep ILP to hide L2/L3 latency; xyz read ONCE (was 16x).
__global__ __launch_bounds__(256) void hash_enc6_kernel(
    const float* __restrict__ xyz, const float* __restrict__ amin,
    const float* __restrict__ amax, const uint32_t* __restrict__ tbl8,
    const uint32_t* __restrict__ dtbl, uint32_t* __restrict__ featw,
    int N, int T, ResArr ra, DOff doffs) {
  __shared__ float xs_lds[768];
  int tid = threadIdx.x;
  int pblk = blockIdx.x * 256;
  int p = pblk + tid;

  // block-cooperative coalesced xyz stage
  int total = N * 3;
#pragma unroll
  for (int k = 0; k < 3; ++k) {
    int g = pblk * 3 + k * 256 + tid;
    xs_lds[k * 256 + tid] = (g < total) ? xyz[g] : 0.f;
  }
  __syncthreads();

  if (p >= N) return;

  float mn0 = amin[0], mn1 = amin[1], mn2 = amin[2];
  float x = (xs_lds[tid * 3 + 0] - mn0) / (amax[0] - mn0);
  float y = (xs_lds[tid * 3 + 1] - mn1) / (amax[1] - mn1);
  float z = (xs_lds[tid * 3 + 2] - mn2) / (amax[2] - mn2);
  const float hi = 1.0f - 1e-6f;
  x = fminf(fmaxf(x, 0.f), hi);
  y = fminf(fmaxf(y, 0.f), hi);
  z = fminf(fmaxf(z, 0.f), hi);

  uint32_t mask = (uint32_t)(T - 1);
  const float s = 1.0f / 2048.0f;
  uint32_t feats[16];

#pragma unroll
  for (int lvl = 0; lvl < 16; ++lvl) {
    float res = ra.r[lvl];
    float xs0 = x * res, xs1 = y * res, xs2 = z * res;
    float c0 = floorf(xs0), c1 = floorf(xs1), c2 = floorf(xs2);
    float fr0 = xs0 - c0, fr1 = xs1 - c1, fr2 = xs2 - c2;
    int j0 = (int)c0, j1 = (int)c1, j2 = (int)c2;
    float wx0 = 1.f - fr0, wy0 = 1.f - fr1, wz0 = 1.f - fr2;
    float acc0 = 0.f, acc1 = 0.f;

    if (lvl < 5) {
      // dense path: 4 loads, z-pair inside each dword
      int r = (int)res, rp = r + 1;
      const uint32_t* dtb = dtbl + doffs.off[lvl];
#pragma unroll
      for (int c = 0; c < 4; ++c) {
        int bx = c & 1, by = c >> 1;
        int a = ((j0 + bx) * rp + (j1 + by)) * r + j2;
        uint32_t u = dtb[a];
        float b0 = (float)((int)(u << 24) >> 24);
        float b1v = (float)((int)(u << 16) >> 24);
        float b2 = (float)((int)(u << 8) >> 24);
        float b3 = (float)((int)u >> 24);
        float g0 = b0 + fr2 * (b2 - b0);
        float g1 = b1v + fr2 * (b3 - b1v);
        float wxy = (bx ? fr0 : wx0) * (by ? fr1 : wy0);
        acc0 += wxy * g0;
        acc1 += wxy * g1;
      }
    } else {
      // hashed path: 4 (by,bz) passes; x-pair in-dword + odd fixup
      uint32_t j0u = (uint32_t)j0;
      const uint32_t* tb = tbl8 + (size_t)lvl * (size_t)(T >> 1);
      uint32_t hy0 = (uint32_t)j1 * 2654435761u, hy1 = hy0 + 2654435761u;
      uint32_t hz0 = (uint32_t)j2 * 805459861u, hz1 = hz0 + 805459861u;
      bool odd = (j0u & 1u) != 0u;
#pragma unroll
      for (int c = 0; c < 4; ++c) {
        uint32_t hyz = ((c & 1) ? hy1 : hy0) ^ ((c >> 1) ? hz1 : hz0);
        uint32_t idx0 = (j0u ^ hyz) & mask;
        uint32_t idx1 = ((j0u + 1u) ^ hyz) & mask;
        uint32_t u = tb[idx0 >> 1];
        uint32_t u2 = u;  // even j0: same dword holds both x-corners
        if (odd) u2 = tb[idx1 >> 1];
        uint32_t ha = (idx0 & 1u) ? (u >> 16) : (u & 0xFFFFu);
        uint32_t hb = (idx1 & 1u) ? (u2 >> 16) : (u2 & 0xFFFFu);
        float fa0 = (float)((int)(ha << 24) >> 24);
        float fa1 = (float)((int)(ha << 16) >> 24);
        float fb0 = (float)((int)(hb << 24) >> 24);
        float fb1 = (float)((int)(hb << 16) >> 24);
        float g0 = fa0 + fr0 * (fb0 - fa0);
        float g1 = fa1 + fr0 * (fb1 - fa1);
        float wyz = ((c & 1) ? fr1 : wy0) * ((c >> 1) ? fr2 : wz0);
        acc0 += wyz * g0;
        acc1 += wyz * g1;
      }
    }
    feats[lvl] = (uint32_t)f2bf(acc0 * s) | ((uint32_t)f2bf(acc1 * s) << 16);
  }

#pragma unroll
  for (int lvl = 0; lvl < 16; ++lvl)
    featw[(size_t)lvl * N + p] = feats[lvl];
}

// ---------------- fused MLP (MFMA bf16) + epilogue + loss partials -------
__global__ __launch_bounds__(256) void mlp_kernel(
    const uint32_t* __restrict__ featw, const uint16_t* __restrict__ pW1,
    const uint16_t* __restrict__ pW2, const uint16_t* __restrict__ pW3,
    const float* __restrict__ b1p, const float* __restrict__ b2,
    const float* __restrict__ b3, const float* __restrict__ xyz,
    const float* __restrict__ scal, const float* __restrict__ rot,
    float* __restrict__ out, float* __restrict__ partial, int N) {
  __shared__ alignas(16) uint16_t h1_lds[4 * 16 * 136];
  __shared__ alignas(16) uint16_t h2_lds[4 * 16 * 136];
  __shared__ float dd[4][16][12];
  __shared__ float bl[4][3];

  int tid = threadIdx.x, wv = tid >> 6, lane = tid & 63;
  int rowi = lane & 15, g = lane >> 4;
  int pbase = blockIdx.x * 64 + wv * 16;
  int prow = pbase + rowi;
  int pc = min(prow, N - 1);

  union { uint32_t u[4]; short8 v; } cva;
#pragma unroll
  for (int jj = 0; jj < 4; ++jj)
    cva.u[jj] = featw[(size_t)(g * 4 + jj) * N + pc];
  short8 a1 = cva.v;

  uint16_t* h1w = &h1_lds[wv * 16 * 136];
  const short8* w1f = (const short8*)pW1;
#pragma unroll
  for (int t = 0; t < 8; ++t) {
    float bb = b1p[t * 16 + rowi];
    f32x4 c = {bb, bb, bb, bb};
    c = __builtin_amdgcn_mfma_f32_16x16x32_bf16(a1, w1f[t * 64 + lane], c, 0, 0, 0);
#pragma unroll
    for (int r = 0; r < 4; ++r)
      h1w[(4 * g + r) * 136 + t * 16 + rowi] = f2bf(fmaxf(c[r], 0.f));
  }
  __syncthreads();

  short8 a2[4];
#pragma unroll
  for (int s = 0; s < 4; ++s)
    a2[s] = *(const short8*)&h1w[rowi * 136 + s * 32 + g * 8];
  const short8* w2f = (const short8*)pW2;
  uint16_t* h2w = &h2_lds[wv * 16 * 136];
#pragma unroll
  for (int t = 0; t < 8; ++t) {
    float bb = b2[t * 16 + rowi];
    f32x4 c = {bb, bb, bb, bb};
#pragma unroll
    for (int s = 0; s < 4; ++s)
      c = __builtin_amdgcn_mfma_f32_16x16x32_bf16(a2[s], w2f[(t * 4 + s) * 64 + lane], c, 0, 0, 0);
#pragma unroll
    for (int r = 0; r < 4; ++r)
      h2w[(4 * g + r) * 136 + t * 16 + rowi] = f2bf(fmaxf(c[r], 0.f));
  }
  __syncthreads();

  short8 a3[4];
#pragma unroll
  for (int s = 0; s < 4; ++s)
    a3[s] = *(const short8*)&h2w[rowi * 136 + s * 32 + g * 8];
  const short8* w3f = (const short8*)pW3;
#pragma unroll
  for (int t = 0; t < 3; ++t) {
    int col = t * 16 + rowi;
    float bb = (col < 42) ? b3[col] : 0.f;
    f32x4 c = {bb, bb, bb, bb};
#pragma unroll
    for (int s = 0; s < 4; ++s)
      c = __builtin_amdgcn_mfma_f32_16x16x32_bf16(a3[s], w3f[(t * 4 + s) * 64 + lane], c, 0, 0, 0);
    if (col >= 10 && col < 42) {
#pragma unroll
      for (int r = 0; r < 4; ++r) {
        int p = pbase + 4 * g + r;
        if (p < N) out[(size_t)p * 42 + col] = c[r];
      }
    } else if (col < 10) {
#pragma unroll
      for (int r = 0; r < 4; ++r) dd[wv][4 * g + r][col] = c[r];
    }
  }
  __syncthreads();

  float lx = 0.f, ls = 0.f, lr = 0.f;
  if (lane < 16) {
    int p = pbase + lane;
    if (p < N) {
      float d0 = dd[wv][lane][0], d1 = dd[wv][lane][1], d2 = dd[wv][lane][2];
      float d3 = dd[wv][lane][3], d4 = dd[wv][lane][4], d5 = dd[wv][lane][5];
      float d6 = dd[wv][lane][6], d7 = dd[wv][lane][7], d8 = dd[wv][lane][8];
      float d9 = dd[wv][lane][9];
      size_t ob = (size_t)p * 42;
      out[ob + 0] = xyz[p * 3 + 0] + d0;
      out[ob + 1] = xyz[p * 3 + 1] + d1;
      out[ob + 2] = xyz[p * 3 + 2] + d2;
      out[ob + 3] = scal[p * 3 + 0] + d3;
      out[ob + 4] = scal[p * 3 + 1] + d4;
      out[ob + 5] = scal[p * 3 + 2] + d5;
      out[ob + 6] = rot[p * 4 + 0] + d6;
      out[ob + 7] = rot[p * 4 + 1] + d7;
      out[ob + 8] = rot[p * 4 + 2] + d8;
      out[ob + 9] = rot[p * 4 + 3] + d9;
      lx = sqrtf(d0 * d0 + d1 * d1 + d2 * d2);
      ls = fabsf(d3) + fabsf(d4) + fabsf(d5);
      lr = fabsf(d6) + fabsf(d7) + fabsf(d8) + fabsf(d9);
    }
  }
#pragma unroll
  for (int off = 32; off; off >>= 1) {
    lx += __shfl_xor(lx, off);
    ls += __shfl_xor(ls, off);
    lr += __shfl_xor(lr, off);
  }
  if (lane == 0) { bl[wv][0] = lx; bl[wv][1] = ls; bl[wv][2] = lr; }
  __syncthreads();
  if (tid == 0) {
    partial[(size_t)blockIdx.x * 3 + 0] = bl[0][0] + bl[1][0] + bl[2][0] + bl[3][0];
    partial[(size_t)blockIdx.x * 3 + 1] = bl[0][1] + bl[1][1] + bl[2][1] + bl[3][1];
    partial[(size_t)blockIdx.x * 3 + 2] = bl[0][2] + bl[1][2] + bl[2][2] + bl[3][2];
  }
}

// ---------------- finalize: losses row N ---------------------------------
__global__ void finalize_kernel(const float* __restrict__ partial, int nb,
                                float* __restrict__ out, int N) {
  int tid = threadIdx.x, wv = tid >> 6, lane = tid & 63;
  __shared__ float red[4][3];
  float s0 = 0.f, s1 = 0.f, s2 = 0.f;
  for (int i = tid; i < nb; i += 256) {
    s0 += partial[(size_t)i * 3 + 0];
    s1 += partial[(size_t)i * 3 + 1];
    s2 += partial[(size_t)i * 3 + 2];
  }
#pragma unroll
  for (int off = 32; off; off >>= 1) {
    s0 += __shfl_xor(s0, off);
    s1 += __shfl_xor(s1, off);
    s2 += __shfl_xor(s2, off);
  }
  if (lane == 0) { red[wv][0] = s0; red[wv][1] = s1; red[wv][2] = s2; }
  __syncthreads();
  size_t base = (size_t)N * 42;
  if (tid == 0) {
    float t0 = red[0][0] + red[1][0] + red[2][0] + red[3][0];
    float t1 = red[0][1] + red[1][1] + red[2][1] + red[3][1];
    float t2 = red[0][2] + red[1][2] + red[2][2] + red[3][2];
    out[base + 0] = t0 / (float)N;
    out[base + 1] = t1 / (float)N;
    out[base + 2] = t2 / (float)N;
  }
  if (tid >= 3 && tid < 42) out[base + tid] = 0.f;
}

extern "C" void kernel_launch(void* const* d_in, const int* in_sizes, int n_in,
                              void* d_out, int out_size, void* d_ws,
                              size_t ws_size, hipStream_t stream) {
  const float* xyz = (const float*)d_in[0];
  const float* scal = (const float*)d_in[1];
  const float* rot = (const float*)d_in[2];
  const float* cond = (const float*)d_in[3];
  const float* table = (const float*)d_in[4];
  const float* amin = (const float*)d_in[5];
  const float* amax = (const float*)d_in[6];
  const float* W1 = (const float*)d_in[7];
  const float* b1 = (const float*)d_in[8];
  const float* W2 = (const float*)d_in[9];
  const float* b2 = (const float*)d_in[10];
  const float* W3 = (const float*)d_in[11];
  const float* b3 = (const float*)d_in[12];
  float* out = (float*)d_out;

  int N = in_sizes[0] / 3;
  int T = in_sizes[4] / (16 * 2);
  int nb_mlp = (N + 63) / 64;

  ResArr ra;
  double growth = std::pow(2048.0 / 16.0, 1.0 / 15.0);
  for (int l = 0; l < 16; ++l)
    ra.r[l] = (float)std::floor(16.0 * std::pow(growth, (double)l));

  DOff doffs;
  int doff = 0;
  int dmaxn = 0;
  for (int l = 0; l < 5; ++l) {
    doffs.off[l] = doff;
    int r = (int)ra.r[l];
    int n = (r + 1) * (r + 1) * r;
    if (n > dmaxn) dmaxn = n;
    doff += n;
  }

  char* ws = (char*)d_ws;
  size_t off = 0;
  size_t featB = (size_t)16 * (size_t)N * 4;
  uint32_t* featw = (uint32_t*)(ws + off); off += featB;
  uint16_t* pW1 = (uint16_t*)(ws + off); off += 4096 * 2;
  uint16_t* pW2 = (uint16_t*)(ws + off); off += 16384 * 2;
  uint16_t* pW3 = (uint16_t*)(ws + off); off += 6144 * 2;
  float* b1p = (float*)(ws + off); off += 128 * 4;
  float* partial = (float*)(ws + off); off += (size_t)nb_mlp * 3 * 4;
  off = (off + 15) & ~(size_t)15;
  uint32_t* tbl8 = (uint32_t*)(ws + off); off += (size_t)16 * (size_t)(T >> 1) * 4;
  uint32_t* dtbl = (uint32_t*)(ws + off); off += (size_t)doff * 4;

  prep_pack_kernel<<<104, 256, 0, stream>>>(W1, W2, W3, pW1, pW2, pW3);
  prep_b1p_kernel<<<1, 128, 0, stream>>>(b1, cond, W1, b1p);

  int n_i8 = 16 * (T >> 1);
  tbl_i8_kernel<<<2048, 256, 0, stream>>>((const float4*)table, tbl8, n_i8);
  dense_build_kernel<<<dim3((dmaxn + 255) / 256, 5), 256, 0, stream>>>(
      table, dtbl, doffs, ra, T);

  hash_enc6_kernel<<<(N + 255) / 256, 256, 0, stream>>>(
      xyz, amin, amax, tbl8, dtbl, featw, N, T, ra, doffs);

  mlp_kernel<<<nb_mlp, 256, 0, stream>>>(featw, pW1, pW2, pW3, b1p, b2, b3,
                                         xyz, scal, rot, out, partial, N);
  finalize_kernel<<<1, 256, 0, stream>>>(partial, nb_mlp, out, N);
}

// Round 7
// 283.321 us; speedup vs baseline: 1.2128x; 1.2128x over previous
//
#include <hip/hip_runtime.h>
#include <stdint.h>
#include <cmath>

typedef short short8 __attribute__((ext_vector_type(8)));
typedef float f32x4 __attribute__((ext_vector_type(4)));

struct ResArr { float r[16]; };
struct DOff { int off[5]; };

__device__ __forceinline__ uint16_t f2bf(float f) {
  uint32_t u;
  __builtin_memcpy(&u, &f, 4);
  uint32_t r = (u + 0x7FFFu + ((u >> 16) & 1u)) >> 16;  // RNE
  return (uint16_t)r;
}

__device__ __forceinline__ uint32_t enc8(float v) {
  int q = __float2int_rn(v * 2048.0f);
  q = max(-127, min(127, q));
  return (uint32_t)(q & 0xFF);
}

// ---------------- prep: f32 table -> int8 pairs, hashed levels 5..15 -----
__global__ __launch_bounds__(256) void tbl_i8_kernel(
    const float4* __restrict__ t4, uint32_t* __restrict__ o, int n) {
  int i = blockIdx.x * 256 + threadIdx.x;
  int stride = gridDim.x * 256;
  for (; i < n; i += stride) {
    float4 v = t4[i];
    o[i] = enc8(v.x) | (enc8(v.y) << 8) | (enc8(v.z) << 16) | (enc8(v.w) << 24);
  }
}

// ---------------- prep: dense re-indexed tables for levels 0..4 ----------
__global__ __launch_bounds__(256) void dense_build_kernel(
    const float* __restrict__ tablef, uint32_t* __restrict__ dt,
    DOff doffs, ResArr ra, int T) {
  int lvl = blockIdx.y;  // 0..4
  int r = (int)ra.r[lvl];
  int rp = r + 1;
  int n = rp * rp * r;
  uint32_t mask = (uint32_t)(T - 1);
  const float* tb = tablef + (size_t)lvl * (size_t)T * 2;
  uint32_t* out = dt + doffs.off[lvl];
  for (int i = blockIdx.x * 256 + threadIdx.x; i < n; i += gridDim.x * 256) {
    int z = i % r;
    int t = i / r;
    int y = t % rp;
    int x = t / rp;
    uint32_t hy = (uint32_t)y * 2654435761u;
    uint32_t h0 = ((uint32_t)x ^ hy ^ (uint32_t)z * 805459861u) & mask;
    uint32_t h1 = ((uint32_t)x ^ hy ^ (uint32_t)(z + 1) * 805459861u) & mask;
    float a0 = tb[h0 * 2], a1 = tb[h0 * 2 + 1];
    float c0 = tb[h1 * 2], c1 = tb[h1 * 2 + 1];
    out[i] = enc8(a0) | (enc8(a1) << 8) | (enc8(c0) << 16) | (enc8(c1) << 24);
  }
}

// ---------------- prep: pack weights into MFMA B-fragment order (bf16) ----
__global__ __launch_bounds__(256) void prep_pack_kernel(
    const float* __restrict__ W1, const float* __restrict__ W2,
    const float* __restrict__ W3, uint16_t* __restrict__ pW1,
    uint16_t* __restrict__ pW2, uint16_t* __restrict__ pW3) {
  int i = blockIdx.x * 256 + threadIdx.x;
  if (i < 4096) {
    int j = i & 7, lane = (i >> 3) & 63, t = i >> 9;
    int k = (lane >> 4) * 8 + j, col = t * 16 + (lane & 15);
    pW1[i] = f2bf(W1[k * 128 + col]);
  } else if (i < 20480) {
    int q = i - 4096;
    int j = q & 7, lane = (q >> 3) & 63, st = q >> 9;
    int s = st & 3, t = st >> 2;
    int k = s * 32 + (lane >> 4) * 8 + j, col = t * 16 + (lane & 15);
    pW2[q] = f2bf(W2[k * 128 + col]);
  } else if (i < 26624) {
    int q = i - 20480;
    int j = q & 7, lane = (q >> 3) & 63, st = q >> 9;
    int s = st & 3, t = st >> 2;
    int k = s * 32 + (lane >> 4) * 8 + j, col = t * 16 + (lane & 15);
    pW3[q] = (col < 42) ? f2bf(W3[k * 42 + col]) : (uint16_t)0;
  }
}

// b1' = b1 + cond @ W1[32:160]
__global__ void prep_b1p_kernel(const float* __restrict__ b1,
                                const float* __restrict__ cond,
                                const float* __restrict__ W1,
                                float* __restrict__ b1p) {
  int j = threadIdx.x;  // 128 threads
  float acc = b1[j];
  for (int c = 0; c < 128; ++c) acc += cond[c] * W1[(32 + c) * 128 + j];
  b1p[j] = acc;
}

// ---------------- hash grid encode v7: 4 levels per thread ---------------
// grid (nx, 4): group g handles levels 4g..4g+3. Temporal group-major
// execution keeps <=4MB of tables L2-resident per XCD (like v5's per-level
// locality) while giving each thread 16-24 independent gathers (ILP to hide
// L2 latency, which v5 lacked). xyz read 4x instead of 16x.
__global__ __launch_bounds__(256) void hash_enc7_kernel(
    const float* __restrict__ xyz, const float* __restrict__ amin,
    const float* __restrict__ amax, const uint32_t* __restrict__ tbl8,
    const uint32_t* __restrict__ dtbl, uint32_t* __restrict__ featw,
    int N, int T, ResArr ra, DOff doffs) {
  int g = blockIdx.y;  // level group
  int p = blockIdx.x * 256 + threadIdx.x;
  if (p >= N) return;

  float mn0 = amin[0], mn1 = amin[1], mn2 = amin[2];
  float x = (xyz[p * 3 + 0] - mn0) / (amax[0] - mn0);
  float y = (xyz[p * 3 + 1] - mn1) / (amax[1] - mn1);
  float z = (xyz[p * 3 + 2] - mn2) / (amax[2] - mn2);
  const float hi = 1.0f - 1e-6f;
  x = fminf(fmaxf(x, 0.f), hi);
  y = fminf(fmaxf(y, 0.f), hi);
  z = fminf(fmaxf(z, 0.f), hi);

  uint32_t mask = (uint32_t)(T - 1);
  const float s = 1.0f / 2048.0f;
  uint32_t feats[4];

#pragma unroll
  for (int q = 0; q < 4; ++q) {
    int lvl = g * 4 + q;
    float res = ra.r[lvl];
    float xs0 = x * res, xs1 = y * res, xs2 = z * res;
    float c0 = floorf(xs0), c1 = floorf(xs1), c2 = floorf(xs2);
    float fr0 = xs0 - c0, fr1 = xs1 - c1, fr2 = xs2 - c2;
    int j0 = (int)c0, j1 = (int)c1, j2 = (int)c2;
    float wx0 = 1.f - fr0, wy0 = 1.f - fr1, wz0 = 1.f - fr2;
    float acc0 = 0.f, acc1 = 0.f;

    if (lvl < 5) {
      // dense path: 4 loads, z-pair inside each dword
      int r = (int)res, rp = r + 1;
      const uint32_t* dtb = dtbl + doffs.off[lvl];
#pragma unroll
      for (int c = 0; c < 4; ++c) {
        int bx = c & 1, by = c >> 1;
        int a = ((j0 + bx) * rp + (j1 + by)) * r + j2;
        uint32_t u = dtb[a];
        float b0 = (float)((int)(u << 24) >> 24);
        float b1v = (float)((int)(u << 16) >> 24);
        float b2 = (float)((int)(u << 8) >> 24);
        float b3 = (float)((int)u >> 24);
        float g0 = b0 + fr2 * (b2 - b0);
        float g1 = b1v + fr2 * (b3 - b1v);
        float wxy = (bx ? fr0 : wx0) * (by ? fr1 : wy0);
        acc0 += wxy * g0;
        acc1 += wxy * g1;
      }
    } else {
      // hashed path: 4 (by,bz) passes; x-pair in-dword + odd fixup
      uint32_t j0u = (uint32_t)j0;
      const uint32_t* tb = tbl8 + (size_t)(lvl - 5) * (size_t)(T >> 1);
      uint32_t hy0 = (uint32_t)j1 * 2654435761u, hy1 = hy0 + 2654435761u;
      uint32_t hz0 = (uint32_t)j2 * 805459861u, hz1 = hz0 + 805459861u;
      bool odd = (j0u & 1u) != 0u;
#pragma unroll
      for (int c = 0; c < 4; ++c) {
        uint32_t hyz = ((c & 1) ? hy1 : hy0) ^ ((c >> 1) ? hz1 : hz0);
        uint32_t idx0 = (j0u ^ hyz) & mask;
        uint32_t idx1 = ((j0u + 1u) ^ hyz) & mask;
        uint32_t u = tb[idx0 >> 1];
        uint32_t u2 = u;  // even j0: same dword holds both x-corners
        if (odd) u2 = tb[idx1 >> 1];
        uint32_t ha = (idx0 & 1u) ? (u >> 16) : (u & 0xFFFFu);
        uint32_t hb = (idx1 & 1u) ? (u2 >> 16) : (u2 & 0xFFFFu);
        float fa0 = (float)((int)(ha << 24) >> 24);
        float fa1 = (float)((int)(ha << 16) >> 24);
        float fb0 = (float)((int)(hb << 24) >> 24);
        float fb1 = (float)((int)(hb << 16) >> 24);
        float g0 = fa0 + fr0 * (fb0 - fa0);
        float g1 = fa1 + fr0 * (fb1 - fa1);
        float wyz = ((c & 1) ? fr1 : wy0) * ((c >> 1) ? fr2 : wz0);
        acc0 += wyz * g0;
        acc1 += wyz * g1;
      }
    }
    feats[q] = (uint32_t)f2bf(acc0 * s) | ((uint32_t)f2bf(acc1 * s) << 16);
  }

#pragma unroll
  for (int q = 0; q < 4; ++q)
    featw[(size_t)(g * 4 + q) * N + p] = feats[q];
}

// ---------------- fused MLP (MFMA bf16) + epilogue + loss partials -------
__global__ __launch_bounds__(256) void mlp_kernel(
    const uint32_t* __restrict__ featw, const uint16_t* __restrict__ pW1,
    const uint16_t* __restrict__ pW2, const uint16_t* __restrict__ pW3,
    const float* __restrict__ b1p, const float* __restrict__ b2,
    const float* __restrict__ b3, const float* __restrict__ xyz,
    const float* __restrict__ scal, const float* __restrict__ rot,
    float* __restrict__ out, float* __restrict__ partial, int N) {
  __shared__ alignas(16) uint16_t h1_lds[4 * 16 * 136];
  __shared__ alignas(16) uint16_t h2_lds[4 * 16 * 136];
  __shared__ float dd[4][16][12];
  __shared__ float bl[4][3];

  int tid = threadIdx.x, wv = tid >> 6, lane = tid & 63;
  int rowi = lane & 15, g = lane >> 4;
  int pbase = blockIdx.x * 64 + wv * 16;
  int prow = pbase + rowi;
  int pc = min(prow, N - 1);

  union { uint32_t u[4]; short8 v; } cva;
#pragma unroll
  for (int jj = 0; jj < 4; ++jj)
    cva.u[jj] = featw[(size_t)(g * 4 + jj) * N + pc];
  short8 a1 = cva.v;

  uint16_t* h1w = &h1_lds[wv * 16 * 136];
  const short8* w1f = (const short8*)pW1;
#pragma unroll
  for (int t = 0; t < 8; ++t) {
    float bb = b1p[t * 16 + rowi];
    f32x4 c = {bb, bb, bb, bb};
    c = __builtin_amdgcn_mfma_f32_16x16x32_bf16(a1, w1f[t * 64 + lane], c, 0, 0, 0);
#pragma unroll
    for (int r = 0; r < 4; ++r)
      h1w[(4 * g + r) * 136 + t * 16 + rowi] = f2bf(fmaxf(c[r], 0.f));
  }
  __syncthreads();

  short8 a2[4];
#pragma unroll
  for (int s = 0; s < 4; ++s)
    a2[s] = *(const short8*)&h1w[rowi * 136 + s * 32 + g * 8];
  const short8* w2f = (const short8*)pW2;
  uint16_t* h2w = &h2_lds[wv * 16 * 136];
#pragma unroll
  for (int t = 0; t < 8; ++t) {
    float bb = b2[t * 16 + rowi];
    f32x4 c = {bb, bb, bb, bb};
#pragma unroll
    for (int s = 0; s < 4; ++s)
      c = __builtin_amdgcn_mfma_f32_16x16x32_bf16(a2[s], w2f[(t * 4 + s) * 64 + lane], c, 0, 0, 0);
#pragma unroll
    for (int r = 0; r < 4; ++r)
      h2w[(4 * g + r) * 136 + t * 16 + rowi] = f2bf(fmaxf(c[r], 0.f));
  }
  __syncthreads();

  short8 a3[4];
#pragma unroll
  for (int s = 0; s < 4; ++s)
    a3[s] = *(const short8*)&h2w[rowi * 136 + s * 32 + g * 8];
  const short8* w3f = (const short8*)pW3;
#pragma unroll
  for (int t = 0; t < 3; ++t) {
    int col = t * 16 + rowi;
    float bb = (col < 42) ? b3[col] : 0.f;
    f32x4 c = {bb, bb, bb, bb};
#pragma unroll
    for (int s = 0; s < 4; ++s)
      c = __builtin_amdgcn_mfma_f32_16x16x32_bf16(a3[s], w3f[(t * 4 + s) * 64 + lane], c, 0, 0, 0);
    if (col >= 10 && col < 42) {
#pragma unroll
      for (int r = 0; r < 4; ++r) {
        int p = pbase + 4 * g + r;
        if (p < N) out[(size_t)p * 42 + col] = c[r];
      }
    } else if (col < 10) {
#pragma unroll
      for (int r = 0; r < 4; ++r) dd[wv][4 * g + r][col] = c[r];
    }
  }
  __syncthreads();

  float lx = 0.f, ls = 0.f, lr = 0.f;
  if (lane < 16) {
    int p = pbase + lane;
    if (p < N) {
      float d0 = dd[wv][lane][0], d1 = dd[wv][lane][1], d2 = dd[wv][lane][2];
      float d3 = dd[wv][lane][3], d4 = dd[wv][lane][4], d5 = dd[wv][lane][5];
      float d6 = dd[wv][lane][6], d7 = dd[wv][lane][7], d8 = dd[wv][lane][8];
      float d9 = dd[wv][lane][9];
      size_t ob = (size_t)p * 42;
      out[ob + 0] = xyz[p * 3 + 0] + d0;
      out[ob + 1] = xyz[p * 3 + 1] + d1;
      out[ob + 2] = xyz[p * 3 + 2] + d2;
      out[ob + 3] = scal[p * 3 + 0] + d3;
      out[ob + 4] = scal[p * 3 + 1] + d4;
      out[ob + 5] = scal[p * 3 + 2] + d5;
      out[ob + 6] = rot[p * 4 + 0] + d6;
      out[ob + 7] = rot[p * 4 + 1] + d7;
      out[ob + 8] = rot[p * 4 + 2] + d8;
      out[ob + 9] = rot[p * 4 + 3] + d9;
      lx = sqrtf(d0 * d0 + d1 * d1 + d2 * d2);
      ls = fabsf(d3) + fabsf(d4) + fabsf(d5);
      lr = fabsf(d6) + fabsf(d7) + fabsf(d8) + fabsf(d9);
    }
  }
#pragma unroll
  for (int off = 32; off; off >>= 1) {
    lx += __shfl_xor(lx, off);
    ls += __shfl_xor(ls, off);
    lr += __shfl_xor(lr, off);
  }
  if (lane == 0) { bl[wv][0] = lx; bl[wv][1] = ls; bl[wv][2] = lr; }
  __syncthreads();
  if (tid == 0) {
    partial[(size_t)blockIdx.x * 3 + 0] = bl[0][0] + bl[1][0] + bl[2][0] + bl[3][0];
    partial[(size_t)blockIdx.x * 3 + 1] = bl[0][1] + bl[1][1] + bl[2][1] + bl[3][1];
    partial[(size_t)blockIdx.x * 3 + 2] = bl[0][2] + bl[1][2] + bl[2][2] + bl[3][2];
  }
}

// ---------------- finalize: losses row N ---------------------------------
__global__ void finalize_kernel(const float* __restrict__ partial, int nb,
                                float* __restrict__ out, int N) {
  int tid = threadIdx.x, wv = tid >> 6, lane = tid & 63;
  __shared__ float red[4][3];
  float s0 = 0.f, s1 = 0.f, s2 = 0.f;
  for (int i = tid; i < nb; i += 256) {
    s0 += partial[(size_t)i * 3 + 0];
    s1 += partial[(size_t)i * 3 + 1];
    s2 += partial[(size_t)i * 3 + 2];
  }
#pragma unroll
  for (int off = 32; off; off >>= 1) {
    s0 += __shfl_xor(s0, off);
    s1 += __shfl_xor(s1, off);
    s2 += __shfl_xor(s2, off);
  }
  if (lane == 0) { red[wv][0] = s0; red[wv][1] = s1; red[wv][2] = s2; }
  __syncthreads();
  size_t base = (size_t)N * 42;
  if (tid == 0) {
    float t0 = red[0][0] + red[1][0] + red[2][0] + red[3][0];
    float t1 = red[0][1] + red[1][1] + red[2][1] + red[3][1];
    float t2 = red[0][2] + red[1][2] + red[2][2] + red[3][2];
    out[base + 0] = t0 / (float)N;
    out[base + 1] = t1 / (float)N;
    out[base + 2] = t2 / (float)N;
  }
  if (tid >= 3 && tid < 42) out[base + tid] = 0.f;
}

extern "C" void kernel_launch(void* const* d_in, const int* in_sizes, int n_in,
                              void* d_out, int out_size, void* d_ws,
                              size_t ws_size, hipStream_t stream) {
  const float* xyz = (const float*)d_in[0];
  const float* scal = (const float*)d_in[1];
  const float* rot = (const float*)d_in[2];
  const float* cond = (const float*)d_in[3];
  const float* table = (const float*)d_in[4];
  const float* amin = (const float*)d_in[5];
  const float* amax = (const float*)d_in[6];
  const float* W1 = (const float*)d_in[7];
  const float* b1 = (const float*)d_in[8];
  const float* W2 = (const float*)d_in[9];
  const float* b2 = (const float*)d_in[10];
  const float* W3 = (const float*)d_in[11];
  const float* b3 = (const float*)d_in[12];
  float* out = (float*)d_out;

  int N = in_sizes[0] / 3;
  int T = in_sizes[4] / (16 * 2);
  int nb_mlp = (N + 63) / 64;

  ResArr ra;
  double growth = std::pow(2048.0 / 16.0, 1.0 / 15.0);
  for (int l = 0; l < 16; ++l)
    ra.r[l] = (float)std::floor(16.0 * std::pow(growth, (double)l));

  DOff doffs;
  int doff = 0;
  int dmaxn = 0;
  for (int l = 0; l < 5; ++l) {
    doffs.off[l] = doff;
    int r = (int)ra.r[l];
    int n = (r + 1) * (r + 1) * r;
    if (n > dmaxn) dmaxn = n;
    doff += n;
  }

  char* ws = (char*)d_ws;
  size_t off = 0;
  size_t featB = (size_t)16 * (size_t)N * 4;
  uint32_t* featw = (uint32_t*)(ws + off); off += featB;
  uint16_t* pW1 = (uint16_t*)(ws + off); off += 4096 * 2;
  uint16_t* pW2 = (uint16_t*)(ws + off); off += 16384 * 2;
  uint16_t* pW3 = (uint16_t*)(ws + off); off += 6144 * 2;
  float* b1p = (float*)(ws + off); off += 128 * 4;
  float* partial = (float*)(ws + off); off += (size_t)nb_mlp * 3 * 4;
  off = (off + 15) & ~(size_t)15;
  uint32_t* tbl8 = (uint32_t*)(ws + off); off += (size_t)11 * (size_t)(T >> 1) * 4;
  uint32_t* dtbl = (uint32_t*)(ws + off); off += (size_t)doff * 4;

  prep_pack_kernel<<<104, 256, 0, stream>>>(W1, W2, W3, pW1, pW2, pW3);
  prep_b1p_kernel<<<1, 128, 0, stream>>>(b1, cond, W1, b1p);

  // int8 tables only for hashed levels 5..15
  int n_i8 = 11 * (T >> 1);
  const float4* t4base = (const float4*)(table + (size_t)5 * (size_t)T * 2);
  tbl_i8_kernel<<<2048, 256, 0, stream>>>(t4base, tbl8, n_i8);
  dense_build_kernel<<<dim3((dmaxn + 255) / 256, 5), 256, 0, stream>>>(
      table, dtbl, doffs, ra, T);

  dim3 hg((N + 255) / 256, 4, 1);
  hash_enc7_kernel<<<hg, 256, 0, stream>>>(xyz, amin, amax, tbl8, dtbl, featw,
                                           N, T, ra, doffs);

  mlp_kernel<<<nb_mlp, 256, 0, stream>>>(featw, pW1, pW2, pW3, b1p, b2, b3,
                                         xyz, scal, rot, out, partial, N);
  finalize_kernel<<<1, 256, 0, stream>>>(partial, nb_mlp, out, N);
}

// Round 8
// 256.442 us; speedup vs baseline: 1.3399x; 1.1048x over previous
//
#include <hip/hip_runtime.h>
#include <stdint.h>
#include <cmath>

typedef short short8 __attribute__((ext_vector_type(8)));
typedef float f32x4 __attribute__((ext_vector_type(4)));

struct ResArr { float r[16]; };
struct DOff { int off[6]; };

__device__ __forceinline__ uint16_t f2bf(float f) {
  uint32_t u;
  __builtin_memcpy(&u, &f, 4);
  uint32_t r = (u + 0x7FFFu + ((u >> 16) & 1u)) >> 16;  // RNE
  return (uint16_t)r;
}

__device__ __forceinline__ uint32_t enc8(float v) {
  int q = __float2int_rn(v * 2048.0f);
  q = max(-127, min(127, q));
  return (uint32_t)(q & 0xFF);
}

// ---------------- prep: f32 table -> int8 pairs, hashed levels 6..15 -----
__global__ __launch_bounds__(256) void tbl_i8_kernel(
    const float4* __restrict__ t4, uint32_t* __restrict__ o, int n) {
  int i = blockIdx.x * 256 + threadIdx.x;
  int stride = gridDim.x * 256;
  for (; i < n; i += stride) {
    float4 v = t4[i];
    o[i] = enc8(v.x) | (enc8(v.y) << 8) | (enc8(v.z) << 16) | (enc8(v.w) << 24);
  }
}

// ---------------- prep: dense [x][z][y] tables for levels 0..5 -----------
// dword(x,z,y) = int8x4 (f0(x,y,z), f1(x,y,z), f0(x,y,z+1), f1(x,y,z+1)).
// y innermost: the 4 (y,z)-corners of one x-slab sit in TWO ADJACENT dwords
// -> ~1 cache line per slab, 2 lines per point per level (was 4).
__global__ __launch_bounds__(256) void dense_build_kernel(
    const float* __restrict__ tablef, uint32_t* __restrict__ dt,
    DOff doffs, ResArr ra, int T) {
  int lvl = blockIdx.y;  // 0..5
  int r = (int)ra.r[lvl];
  int rp = r + 1;
  int n = rp * r * rp;  // x * z * y
  uint32_t mask = (uint32_t)(T - 1);
  const float* tb = tablef + (size_t)lvl * (size_t)T * 2;
  uint32_t* out = dt + doffs.off[lvl];
  for (int i = blockIdx.x * 256 + threadIdx.x; i < n; i += gridDim.x * 256) {
    int y = i % rp;
    int t = i / rp;
    int z = t % r;
    int x = t / r;
    uint32_t hxy = (uint32_t)x ^ (uint32_t)y * 2654435761u;
    uint32_t h0 = (hxy ^ (uint32_t)z * 805459861u) & mask;
    uint32_t h1 = (hxy ^ (uint32_t)(z + 1) * 805459861u) & mask;
    float a0 = tb[h0 * 2], a1 = tb[h0 * 2 + 1];
    float c0 = tb[h1 * 2], c1 = tb[h1 * 2 + 1];
    out[i] = enc8(a0) | (enc8(a1) << 8) | (enc8(c0) << 16) | (enc8(c1) << 24);
  }
}

// ---------------- prep: pack weights into MFMA B-fragment order (bf16) ----
__global__ __launch_bounds__(256) void prep_pack_kernel(
    const float* __restrict__ W1, const float* __restrict__ W2,
    const float* __restrict__ W3, uint16_t* __restrict__ pW1,
    uint16_t* __restrict__ pW2, uint16_t* __restrict__ pW3) {
  int i = blockIdx.x * 256 + threadIdx.x;
  if (i < 4096) {
    int j = i & 7, lane = (i >> 3) & 63, t = i >> 9;
    int k = (lane >> 4) * 8 + j, col = t * 16 + (lane & 15);
    pW1[i] = f2bf(W1[k * 128 + col]);
  } else if (i < 20480) {
    int q = i - 4096;
    int j = q & 7, lane = (q >> 3) & 63, st = q >> 9;
    int s = st & 3, t = st >> 2;
    int k = s * 32 + (lane >> 4) * 8 + j, col = t * 16 + (lane & 15);
    pW2[q] = f2bf(W2[k * 128 + col]);
  } else if (i < 26624) {
    int q = i - 20480;
    int j = q & 7, lane = (q >> 3) & 63, st = q >> 9;
    int s = st & 3, t = st >> 2;
    int k = s * 32 + (lane >> 4) * 8 + j, col = t * 16 + (lane & 15);
    pW3[q] = (col < 42) ? f2bf(W3[k * 42 + col]) : (uint16_t)0;
  }
}

// b1' = b1 + cond @ W1[32:160]
__global__ void prep_b1p_kernel(const float* __restrict__ b1,
                                const float* __restrict__ cond,
                                const float* __restrict__ W1,
                                float* __restrict__ b1p) {
  int j = threadIdx.x;  // 128 threads
  float acc = b1[j];
  for (int c = 0; c < 128; ++c) acc += cond[c] * W1[(32 + c) * 128 + j];
  b1p[j] = acc;
}

// ---------------- hash grid encode v8: level-major + dense6 [x][z][y] ----
// Levels 0-5: 2-line dense slabs. Levels 6-15: int8-pair hashed (v5 path).
__global__ __launch_bounds__(256) void hash_enc8_kernel(
    const float* __restrict__ xyz, const float* __restrict__ amin,
    const float* __restrict__ amax, const uint32_t* __restrict__ tbl8,
    const uint32_t* __restrict__ dtbl, uint32_t* __restrict__ featw,
    int N, int T, ResArr ra, DOff doffs) {
  int lvl = blockIdx.y;
  int p = blockIdx.x * 256 + threadIdx.x;
  if (p >= N) return;

  float mn0 = amin[0], mn1 = amin[1], mn2 = amin[2];
  float x = (xyz[p * 3 + 0] - mn0) / (amax[0] - mn0);
  float y = (xyz[p * 3 + 1] - mn1) / (amax[1] - mn1);
  float z = (xyz[p * 3 + 2] - mn2) / (amax[2] - mn2);
  const float hi = 1.0f - 1e-6f;
  x = fminf(fmaxf(x, 0.f), hi);
  y = fminf(fmaxf(y, 0.f), hi);
  z = fminf(fmaxf(z, 0.f), hi);

  float res = ra.r[lvl];
  float xs0 = x * res, xs1 = y * res, xs2 = z * res;
  float c0 = floorf(xs0), c1 = floorf(xs1), c2 = floorf(xs2);
  float fr0 = xs0 - c0, fr1 = xs1 - c1, fr2 = xs2 - c2;
  int j0 = (int)c0, j1 = (int)c1, j2 = (int)c2;

  float wy0 = 1.f - fr1, wz0 = 1.f - fr2;
  float acc0 = 0.f, acc1 = 0.f;

  if (lvl < 6) {
    // dense path: 2 x-slabs, each = 2 adjacent dwords (4 corners)
    int r = (int)res, rp = r + 1;
    const uint32_t* dtb = dtbl + doffs.off[lvl];
#pragma unroll
    for (int bx = 0; bx < 2; ++bx) {
      int base = ((j0 + bx) * r + j2) * rp + j1;
      uint32_t u0 = dtb[base];      // y = j1  : f(z), f(z+1)
      uint32_t u1 = dtb[base + 1];  // y = j1+1: f(z), f(z+1)
      float a0 = (float)((int)(u0 << 24) >> 24);
      float a1 = (float)((int)(u0 << 16) >> 24);
      float a2 = (float)((int)(u0 << 8) >> 24);
      float a3 = (float)((int)u0 >> 24);
      float b0 = (float)((int)(u1 << 24) >> 24);
      float b1v = (float)((int)(u1 << 16) >> 24);
      float b2 = (float)((int)(u1 << 8) >> 24);
      float b3 = (float)((int)u1 >> 24);
      float gy0_0 = a0 + fr2 * (a2 - a0), gy0_1 = a1 + fr2 * (a3 - a1);
      float gy1_0 = b0 + fr2 * (b2 - b0), gy1_1 = b1v + fr2 * (b3 - b1v);
      float h0 = gy0_0 + fr1 * (gy1_0 - gy0_0);
      float h1v = gy0_1 + fr1 * (gy1_1 - gy0_1);
      float wx = bx ? fr0 : (1.f - fr0);
      acc0 += wx * h0;
      acc1 += wx * h1v;
    }
  } else {
    // hashed path: 4 (by,bz) passes; x-pair in-dword + odd fixup
    uint32_t j0u = (uint32_t)j0;
    uint32_t mask = (uint32_t)(T - 1);
    const uint32_t* tb = tbl8 + (size_t)(lvl - 6) * (size_t)(T >> 1);
    uint32_t hy0 = (uint32_t)j1 * 2654435761u, hy1 = hy0 + 2654435761u;
    uint32_t hz0 = (uint32_t)j2 * 805459861u, hz1 = hz0 + 805459861u;
    bool odd = (j0u & 1u) != 0u;
#pragma unroll
    for (int c = 0; c < 4; ++c) {
      uint32_t hyz = ((c & 1) ? hy1 : hy0) ^ ((c >> 1) ? hz1 : hz0);
      uint32_t idx0 = (j0u ^ hyz) & mask;
      uint32_t idx1 = ((j0u + 1u) ^ hyz) & mask;
      uint32_t u = tb[idx0 >> 1];
      uint32_t u2 = u;  // even j0: same dword holds both x-corners
      if (odd) u2 = tb[idx1 >> 1];
      uint32_t ha = (idx0 & 1u) ? (u >> 16) : (u & 0xFFFFu);
      uint32_t hb = (idx1 & 1u) ? (u2 >> 16) : (u2 & 0xFFFFu);
      float fa0 = (float)((int)(ha << 24) >> 24);
      float fa1 = (float)((int)(ha << 16) >> 24);
      float fb0 = (float)((int)(hb << 24) >> 24);
      float fb1 = (float)((int)(hb << 16) >> 24);
      float g0 = fa0 + fr0 * (fb0 - fa0);
      float g1 = fa1 + fr0 * (fb1 - fa1);
      float wyz = ((c & 1) ? fr1 : wy0) * ((c >> 1) ? fr2 : wz0);
      acc0 += wyz * g0;
      acc1 += wyz * g1;
    }
  }

  const float s = 1.0f / 2048.0f;
  featw[(size_t)lvl * N + p] =
      (uint32_t)f2bf(acc0 * s) | ((uint32_t)f2bf(acc1 * s) << 16);
}

// ---------------- fused MLP (MFMA bf16) + epilogue + loss partials -------
__global__ __launch_bounds__(256) void mlp_kernel(
    const uint32_t* __restrict__ featw, const uint16_t* __restrict__ pW1,
    const uint16_t* __restrict__ pW2, const uint16_t* __restrict__ pW3,
    const float* __restrict__ b1p, const float* __restrict__ b2,
    const float* __restrict__ b3, const float* __restrict__ xyz,
    const float* __restrict__ scal, const float* __restrict__ rot,
    float* __restrict__ out, float* __restrict__ partial, int N) {
  __shared__ alignas(16) uint16_t h1_lds[4 * 16 * 136];
  __shared__ alignas(16) uint16_t h2_lds[4 * 16 * 136];
  __shared__ float dd[4][16][12];
  __shared__ float bl[4][3];

  int tid = threadIdx.x, wv = tid >> 6, lane = tid & 63;
  int rowi = lane & 15, g = lane >> 4;
  int pbase = blockIdx.x * 64 + wv * 16;
  int prow = pbase + rowi;
  int pc = min(prow, N - 1);

  union { uint32_t u[4]; short8 v; } cva;
#pragma unroll
  for (int jj = 0; jj < 4; ++jj)
    cva.u[jj] = featw[(size_t)(g * 4 + jj) * N + pc];
  short8 a1 = cva.v;

  uint16_t* h1w = &h1_lds[wv * 16 * 136];
  const short8* w1f = (const short8*)pW1;
#pragma unroll
  for (int t = 0; t < 8; ++t) {
    float bb = b1p[t * 16 + rowi];
    f32x4 c = {bb, bb, bb, bb};
    c = __builtin_amdgcn_mfma_f32_16x16x32_bf16(a1, w1f[t * 64 + lane], c, 0, 0, 0);
#pragma unroll
    for (int r = 0; r < 4; ++r)
      h1w[(4 * g + r) * 136 + t * 16 + rowi] = f2bf(fmaxf(c[r], 0.f));
  }
  __syncthreads();

  short8 a2[4];
#pragma unroll
  for (int s = 0; s < 4; ++s)
    a2[s] = *(const short8*)&h1w[rowi * 136 + s * 32 + g * 8];
  const short8* w2f = (const short8*)pW2;
  uint16_t* h2w = &h2_lds[wv * 16 * 136];
#pragma unroll
  for (int t = 0; t < 8; ++t) {
    float bb = b2[t * 16 + rowi];
    f32x4 c = {bb, bb, bb, bb};
#pragma unroll
    for (int s = 0; s < 4; ++s)
      c = __builtin_amdgcn_mfma_f32_16x16x32_bf16(a2[s], w2f[(t * 4 + s) * 64 + lane], c, 0, 0, 0);
#pragma unroll
    for (int r = 0; r < 4; ++r)
      h2w[(4 * g + r) * 136 + t * 16 + rowi] = f2bf(fmaxf(c[r], 0.f));
  }
  __syncthreads();

  short8 a3[4];
#pragma unroll
  for (int s = 0; s < 4; ++s)
    a3[s] = *(const short8*)&h2w[rowi * 136 + s * 32 + g * 8];
  const short8* w3f = (const short8*)pW3;
#pragma unroll
  for (int t = 0; t < 3; ++t) {
    int col = t * 16 + rowi;
    float bb = (col < 42) ? b3[col] : 0.f;
    f32x4 c = {bb, bb, bb, bb};
#pragma unroll
    for (int s = 0; s < 4; ++s)
      c = __builtin_amdgcn_mfma_f32_16x16x32_bf16(a3[s], w3f[(t * 4 + s) * 64 + lane], c, 0, 0, 0);
    if (col >= 10 && col < 42) {
#pragma unroll
      for (int r = 0; r < 4; ++r) {
        int p = pbase + 4 * g + r;
        if (p < N) out[(size_t)p * 42 + col] = c[r];
      }
    } else if (col < 10) {
#pragma unroll
      for (int r = 0; r < 4; ++r) dd[wv][4 * g + r][col] = c[r];
    }
  }
  __syncthreads();

  float lx = 0.f, ls = 0.f, lr = 0.f;
  if (lane < 16) {
    int p = pbase + lane;
    if (p < N) {
      float d0 = dd[wv][lane][0], d1 = dd[wv][lane][1], d2 = dd[wv][lane][2];
      float d3 = dd[wv][lane][3], d4 = dd[wv][lane][4], d5 = dd[wv][lane][5];
      float d6 = dd[wv][lane][6], d7 = dd[wv][lane][7], d8 = dd[wv][lane][8];
      float d9 = dd[wv][lane][9];
      size_t ob = (size_t)p * 42;
      out[ob + 0] = xyz[p * 3 + 0] + d0;
      out[ob + 1] = xyz[p * 3 + 1] + d1;
      out[ob + 2] = xyz[p * 3 + 2] + d2;
      out[ob + 3] = scal[p * 3 + 0] + d3;
      out[ob + 4] = scal[p * 3 + 1] + d4;
      out[ob + 5] = scal[p * 3 + 2] + d5;
      out[ob + 6] = rot[p * 4 + 0] + d6;
      out[ob + 7] = rot[p * 4 + 1] + d7;
      out[ob + 8] = rot[p * 4 + 2] + d8;
      out[ob + 9] = rot[p * 4 + 3] + d9;
      lx = sqrtf(d0 * d0 + d1 * d1 + d2 * d2);
      ls = fabsf(d3) + fabsf(d4) + fabsf(d5);
      lr = fabsf(d6) + fabsf(d7) + fabsf(d8) + fabsf(d9);
    }
  }
#pragma unroll
  for (int off = 32; off; off >>= 1) {
    lx += __shfl_xor(lx, off);
    ls += __shfl_xor(ls, off);
    lr += __shfl_xor(lr, off);
  }
  if (lane == 0) { bl[wv][0] = lx; bl[wv][1] = ls; bl[wv][2] = lr; }
  __syncthreads();
  if (tid == 0) {
    partial[(size_t)blockIdx.x * 3 + 0] = bl[0][0] + bl[1][0] + bl[2][0] + bl[3][0];
    partial[(size_t)blockIdx.x * 3 + 1] = bl[0][1] + bl[1][1] + bl[2][1] + bl[3][1];
    partial[(size_t)blockIdx.x * 3 + 2] = bl[0][2] + bl[1][2] + bl[2][2] + bl[3][2];
  }
}

// ---------------- finalize: losses row N ---------------------------------
__global__ void finalize_kernel(const float* __restrict__ partial, int nb,
                                float* __restrict__ out, int N) {
  int tid = threadIdx.x, wv = tid >> 6, lane = tid & 63;
  __shared__ float red[4][3];
  float s0 = 0.f, s1 = 0.f, s2 = 0.f;
  for (int i = tid; i < nb; i += 256) {
    s0 += partial[(size_t)i * 3 + 0];
    s1 += partial[(size_t)i * 3 + 1];
    s2 += partial[(size_t)i * 3 + 2];
  }
#pragma unroll
  for (int off = 32; off; off >>= 1) {
    s0 += __shfl_xor(s0, off);
    s1 += __shfl_xor(s1, off);
    s2 += __shfl_xor(s2, off);
  }
  if (lane == 0) { red[wv][0] = s0; red[wv][1] = s1; red[wv][2] = s2; }
  __syncthreads();
  size_t base = (size_t)N * 42;
  if (tid == 0) {
    float t0 = red[0][0] + red[1][0] + red[2][0] + red[3][0];
    float t1 = red[0][1] + red[1][1] + red[2][1] + red[3][1];
    float t2 = red[0][2] + red[1][2] + red[2][2] + red[3][2];
    out[base + 0] = t0 / (float)N;
    out[base + 1] = t1 / (float)N;
    out[base + 2] = t2 / (float)N;
  }
  if (tid >= 3 && tid < 42) out[base + tid] = 0.f;
}

extern "C" void kernel_launch(void* const* d_in, const int* in_sizes, int n_in,
                              void* d_out, int out_size, void* d_ws,
                              size_t ws_size, hipStream_t stream) {
  const float* xyz = (const float*)d_in[0];
  const float* scal = (const float*)d_in[1];
  const float* rot = (const float*)d_in[2];
  const float* cond = (const float*)d_in[3];
  const float* table = (const float*)d_in[4];
  const float* amin = (const float*)d_in[5];
  const float* amax = (const float*)d_in[6];
  const float* W1 = (const float*)d_in[7];
  const float* b1 = (const float*)d_in[8];
  const float* W2 = (const float*)d_in[9];
  const float* b2 = (const float*)d_in[10];
  const float* W3 = (const float*)d_in[11];
  const float* b3 = (const float*)d_in[12];
  float* out = (float*)d_out;

  int N = in_sizes[0] / 3;
  int T = in_sizes[4] / (16 * 2);
  int nb_mlp = (N + 63) / 64;

  ResArr ra;
  double growth = std::pow(2048.0 / 16.0, 1.0 / 15.0);
  for (int l = 0; l < 16; ++l)
    ra.r[l] = (float)std::floor(16.0 * std::pow(growth, (double)l));

  // dense-table dword offsets for levels 0..5 ([x][z][y] layout)
  DOff doffs;
  int doff = 0;
  int dmaxn = 0;
  for (int l = 0; l < 6; ++l) {
    doffs.off[l] = doff;
    int r = (int)ra.r[l];
    int n = (r + 1) * r * (r + 1);
    if (n > dmaxn) dmaxn = n;
    doff += n;
  }

  char* ws = (char*)d_ws;
  size_t off = 0;
  size_t featB = (size_t)16 * (size_t)N * 4;
  uint32_t* featw = (uint32_t*)(ws + off); off += featB;
  uint16_t* pW1 = (uint16_t*)(ws + off); off += 4096 * 2;
  uint16_t* pW2 = (uint16_t*)(ws + off); off += 16384 * 2;
  uint16_t* pW3 = (uint16_t*)(ws + off); off += 6144 * 2;
  float* b1p = (float*)(ws + off); off += 128 * 4;
  float* partial = (float*)(ws + off); off += (size_t)nb_mlp * 3 * 4;
  off = (off + 15) & ~(size_t)15;
  uint32_t* tbl8 = (uint32_t*)(ws + off); off += (size_t)10 * (size_t)(T >> 1) * 4;
  uint32_t* dtbl = (uint32_t*)(ws + off); off += (size_t)doff * 4;

  prep_pack_kernel<<<104, 256, 0, stream>>>(W1, W2, W3, pW1, pW2, pW3);
  prep_b1p_kernel<<<1, 128, 0, stream>>>(b1, cond, W1, b1p);

  // int8 pair tables only for hashed levels 6..15
  int n_i8 = 10 * (T >> 1);
  const float4* t4base = (const float4*)(table + (size_t)6 * (size_t)T * 2);
  tbl_i8_kernel<<<2048, 256, 0, stream>>>(t4base, tbl8, n_i8);
  dense_build_kernel<<<dim3((dmaxn + 255) / 256, 6), 256, 0, stream>>>(
      table, dtbl, doffs, ra, T);

  dim3 hg((N + 255) / 256, 16, 1);
  hash_enc8_kernel<<<hg, 256, 0, stream>>>(xyz, amin, amax, tbl8, dtbl, featw,
                                           N, T, ra, doffs);

  mlp_kernel<<<nb_mlp, 256, 0, stream>>>(featw, pW1, pW2, pW3, b1p, b2, b3,
                                         xyz, scal, rot, out, partial, N);
  finalize_kernel<<<1, 256, 0, stream>>>(partial, nb_mlp, out, N);
}